// Round 3
// baseline (169.227 us; speedup 1.0000x reference)
//
#include <hip/hip_runtime.h>

// CompoundClassifier, round 10: MEASUREMENT ROUND.
// Base = r8 (best measured, 113.9us): cvt_w + pq_gemm + edge_mlp.
// Change: edge_mlp runs its (idempotent) edge loop EDGE_REPEAT=3 times so the
// dispatch becomes visible in rocprof's top-5 (all top-5 so far are 43.5us
// harness ws-poison fills; our kernels are each <43.3us and invisible).
// Read-out: dur_us ~= 114 + 2X (X = true edge cost); edge dispatch counters
// (VALUBusy / hbm / FETCH_SIZE / Occupancy) finally characterize the edge
// bottleneck: latency-bound vs L2-thrash vs VALU.
// r9 post-mortem: dropping cvt_w REGRESSED +3us (strided per-block W1 loads
// cost more than the saved launch) -> launch gaps are ~free; r8 structure back.

#define H  128
#define NI 20000
#define NC 10000
#define NE 1000000

#define EDGE_REPEAT 3

typedef _Float16 half8   __attribute__((ext_vector_type(8)));
typedef float    floatx2 __attribute__((ext_vector_type(2)));
typedef float    floatx4 __attribute__((ext_vector_type(4)));

// ws byte layout
#define P8_OFF    0
#define Q8_OFF    (NI * H)                    // 2,560,000
#define WFRAG_B   ((NI + NC) * H)             // 3,840,000 (16B aligned)
// WFRAG: W1 as f16 in MFMA B-fragment order, 64 KB:
//   flat = ((isQ*8 + w*2+nt)*4 + ks)*512 + lane*8 + j
//   holds W1[k][n], k = isQ*128 + ks*32 + (lane>>4)*8 + j,
//                   n = (w)*32 + nt*16 + (lane&15)         (w*2+nt = ntw)

#define PB (NI / 16)   // 1250
#define QB (NC / 16)   // 625

// ---------- fp8 e4m3 helpers (HW path on gfx950; SW fallback for safety) ----
#if __has_builtin(__builtin_amdgcn_cvt_pk_f32_fp8) && __has_builtin(__builtin_amdgcn_cvt_pk_fp8_f32)
#define HW_FP8 1
#else
#define HW_FP8 0
__device__ inline unsigned char enc_e4m3(float x) {
    unsigned s = x < 0.0f ? 0x80u : 0u;
    float a = fminf(fabsf(x), 448.0f);
    if (a < 0.0009765625f) return (unsigned char)s;       // < 2^-10 -> 0
    int e; float m = frexpf(a, &e);                       // a = m*2^e, m in [0.5,1)
    int E = e + 6;                                        // biased exp
    if (E <= 0) {                                         // subnormal: f*2^-9
        int f = (int)rintf(a * 512.0f);
        if (f > 7) return (unsigned char)(s | 0x08);
        return (unsigned char)(s | f);
    }
    int f = (int)rintf((m * 2.0f - 1.0f) * 8.0f);
    if (f == 8) { f = 0; ++E; }
    if (E > 15 || (E == 15 && f > 6)) { E = 15; f = 6; }  // clamp to 448
    return (unsigned char)(s | (E << 3) | f);
}
__device__ inline float dec_e4m3(unsigned char b) {
    int E = (b >> 3) & 15, f = b & 7;
    float v = (E == 0) ? (float)f * 0.001953125f          // f * 2^-9
                       : (float)(8 + f) * exp2f((float)(E - 10));
    return (b & 0x80) ? -v : v;
}
#endif

__device__ inline floatx2 relu2(floatx2 v) {
#if __has_builtin(__builtin_elementwise_max)
    floatx2 z = {0.0f, 0.0f};
    return __builtin_elementwise_max(v, z);
#else
    floatx2 r = { fmaxf(v.x, 0.0f), fmaxf(v.y, 0.0f) };
    return r;
#endif
}

// ---------- one-shot: W1 -> f16 fragment-ordered table ----------
__launch_bounds__(256)
__global__ void cvt_w(const float* __restrict__ W1,   // [256][128] row-major
                      unsigned char* __restrict__ wsb) {
    const int flat = blockIdx.x * 256 + threadIdx.x;   // over 32768
    const int j    = flat & 7;
    const int lane = (flat >> 3) & 63;
    const int ks   = (flat >> 9) & 3;
    const int ntw  = (flat >> 11) & 7;
    const int isQ  = (flat >> 14) & 1;
    const int n = (ntw >> 1) * 32 + (ntw & 1) * 16 + (lane & 15);
    const int k = isQ * 128 + ks * 32 + (lane >> 4) * 8 + j;
    ((_Float16*)(wsb + WFRAG_B))[flat] = (_Float16)W1[k * H + n];
}

// ---------- P/Q precompute: 16x16x32 f16 MFMA, fp8 epilogue ----------
__launch_bounds__(256)
__global__ void pq_gemm(const float* __restrict__ xin,
                        const float* __restrict__ xcmp,
                        const float* __restrict__ b1,
                        unsigned char* __restrict__ wsb) {
    const int b    = blockIdx.x;
    const bool isQ = (b >= PB);
    const int  rb  = (isQ ? b - PB : b) * 16;
    const float* X = isQ ? xcmp : xin;
    unsigned char* OUT8 = wsb + (isQ ? Q8_OFF : P8_OFF);
    const _Float16* wfrag = (const _Float16*)(wsb + WFRAG_B);

    const int lane = threadIdx.x & 63;
    const int w    = threadIdx.x >> 6;
    const int quad = lane >> 4;
    const int m    = lane & 15;

    // B-fragments: lane-contiguous b128 from the fragment-ordered table
    half8 bf[2][4];
    float b1v[2];
#pragma unroll
    for (int nt = 0; nt < 2; ++nt) {
        const int ntw = w * 2 + nt;
#pragma unroll
        for (int ks = 0; ks < 4; ++ks)
            bf[nt][ks] = *(const half8*)(wfrag + (((isQ ? 8 : 0) + ntw) * 4 + ks) * 512 + lane * 8);
        const int n = w * 32 + nt * 16 + m;
        b1v[nt] = isQ ? b1[n] : 0.0f;
    }

    // A-fragments: row rb+m, contiguous 8 floats -> half8
    half8 af[4];
    const float* xr = X + (long)(rb + m) * H + quad * 8;
#pragma unroll
    for (int ks = 0; ks < 4; ++ks) {
        float4 a = *(const float4*)(xr + ks * 32);
        float4 c = *(const float4*)(xr + ks * 32 + 4);
        half8 v = { (_Float16)a.x, (_Float16)a.y, (_Float16)a.z, (_Float16)a.w,
                    (_Float16)c.x, (_Float16)c.y, (_Float16)c.z, (_Float16)c.w };
        af[ks] = v;
    }

    floatx4 acc[2] = { (floatx4)0.0f, (floatx4)0.0f };
#pragma unroll
    for (int ks = 0; ks < 4; ++ks)
#pragma unroll
        for (int nt = 0; nt < 2; ++nt)
            acc[nt] = __builtin_amdgcn_mfma_f32_16x16x32_f16(af[ks], bf[nt][ks], acc[nt], 0, 0, 0);

    // epilogue: +b1, encode fp8, byte stores (rows contiguous in m -> coalesced)
    // C/D: col = lane&15 within n-tile, row = quad*4 + r
#pragma unroll
    for (int nt = 0; nt < 2; ++nt) {
        const int col = w * 32 + nt * 16 + m;
#pragma unroll
        for (int r = 0; r < 4; ++r) {
            const float v = acc[nt][r] + b1v[nt];
#if HW_FP8
            const unsigned u = (unsigned)__builtin_amdgcn_cvt_pk_fp8_f32(v, v, 0, false);
            OUT8[(rb + quad * 4 + r) * H + col] = (unsigned char)(u & 0xff);
#else
            OUT8[(rb + quad * 4 + r) * H + col] = enc_e4m3(v);
#endif
        }
    }
}

// ---------- edge kernel: 8 lanes/edge, fp8 rows, depth-2 pipelined gather ----
// EDGE_REPEAT x the full (idempotent) edge loop: measurement instrumentation.
#define EGRID 2048

__launch_bounds__(256)
__global__ void edge_mlp(const unsigned char* __restrict__ wsb,
                         const int* __restrict__ src_idx,
                         const int* __restrict__ dst_idx,
                         const float* __restrict__ W2,
                         const float* __restrict__ b2p,
                         float* __restrict__ out) {
    const int tid  = threadIdx.x;
    const int c    = tid & 7;       // 16-byte slice of the 128-B row
    const int slot = tid >> 3;      // edge within pass (0..31)

    // W2 slice: 16 floats for cols c*16..c*16+15 (regs, reused ~15 passes)
    floatx2 w2v[8];
#pragma unroll
    for (int i = 0; i < 8; ++i) w2v[i] = *(const floatx2*)(W2 + c * 16 + i * 2);
    const float b2v = b2p[0];

    const unsigned char* P8 = wsb + P8_OFF;
    const unsigned char* Q8 = wsb + Q8_OFF;
    const int estep = 32 * EGRID;

#pragma unroll 1
    for (int rep = 0; rep < EDGE_REPEAT; ++rep) {
        // ---- pipeline prologue: pass-0 rows + pass-1 indices in flight ----
        int e0 = blockIdx.x * 32 + slot;
        int si0 = 0, di0 = 0;
        if (e0 < NE) {
            si0 = __builtin_nontemporal_load(src_idx + e0);
            di0 = __builtin_nontemporal_load(dst_idx + e0);
        }
        uint4 pd0 = *(const uint4*)(P8 + si0 * H + c * 16);
        uint4 qd0 = *(const uint4*)(Q8 + di0 * H + c * 16);

        int e1 = e0 + estep;
        int si1 = 0, di1 = 0;
        if (e1 < NE) {
            si1 = __builtin_nontemporal_load(src_idx + e1);
            di1 = __builtin_nontemporal_load(dst_idx + e1);
        }

        while (e0 < NE) {
            // issue pass-1 row gathers + pass-2 index loads BEFORE computing pass 0
            uint4 pd1 = *(const uint4*)(P8 + si1 * H + c * 16);
            uint4 qd1 = *(const uint4*)(Q8 + di1 * H + c * 16);
            const int e2 = e1 + estep;
            int si2 = 0, di2 = 0;
            if (e2 < NE) {
                si2 = __builtin_nontemporal_load(src_idx + e2);
                di2 = __builtin_nontemporal_load(dst_idx + e2);
            }

            // ---- compute pass 0 (packed-f32: v_pk_add / v_pk_fma) ----
            floatx2 acc2 = {0.0f, 0.0f};
            const unsigned pw[4] = { pd0.x, pd0.y, pd0.z, pd0.w };
            const unsigned qw[4] = { qd0.x, qd0.y, qd0.z, qd0.w };
#pragma unroll
            for (int jw = 0; jw < 4; ++jw) {
#if HW_FP8
                floatx2 pl = __builtin_amdgcn_cvt_pk_f32_fp8((int)pw[jw], false);
                floatx2 ph = __builtin_amdgcn_cvt_pk_f32_fp8((int)pw[jw], true);
                floatx2 ql = __builtin_amdgcn_cvt_pk_f32_fp8((int)qw[jw], false);
                floatx2 qh = __builtin_amdgcn_cvt_pk_f32_fp8((int)qw[jw], true);
#else
                floatx2 pl = { dec_e4m3(pw[jw] & 0xff), dec_e4m3((pw[jw] >> 8) & 0xff) };
                floatx2 ph = { dec_e4m3((pw[jw] >> 16) & 0xff), dec_e4m3(pw[jw] >> 24) };
                floatx2 ql = { dec_e4m3(qw[jw] & 0xff), dec_e4m3((qw[jw] >> 8) & 0xff) };
                floatx2 qh = { dec_e4m3((qw[jw] >> 16) & 0xff), dec_e4m3(qw[jw] >> 24) };
#endif
                acc2 += relu2(pl + ql) * w2v[2 * jw];      // contracts to v_pk_fma_f32
                acc2 += relu2(ph + qh) * w2v[2 * jw + 1];
            }
            float acc = acc2.x + acc2.y;

            // reduce over the 8-lane edge group
            acc += __shfl_xor(acc, 1);
            acc += __shfl_xor(acc, 2);
            acc += __shfl_xor(acc, 4);

            if (c == 0) {
                const float r = 1.0f / (1.0f + expf(-(acc + b2v)));
                __builtin_nontemporal_store(r, out + e0);  // 32 consecutive floats
            }

            // rotate pipeline
            e0 = e1; pd0 = pd1; qd0 = qd1;
            e1 = e2; si1 = si2; di1 = di2;
        }
    }
}

extern "C" void kernel_launch(void* const* d_in, const int* in_sizes, int n_in,
                              void* d_out, int out_size, void* d_ws, size_t ws_size,
                              hipStream_t stream) {
    const float* xin  = (const float*)d_in[0];
    const float* xcmp = (const float*)d_in[1];
    const int*   eidx = (const int*)d_in[2];    // [2,E]: first E src, next E dst
    const float* W1   = (const float*)d_in[3];
    const float* b1   = (const float*)d_in[4];
    const float* W2   = (const float*)d_in[5];
    const float* b2   = (const float*)d_in[6];
    float* out = (float*)d_out;
    unsigned char* wsb = (unsigned char*)d_ws;  // ~3.9 MB used

    hipLaunchKernelGGL(cvt_w,   dim3(128),     dim3(256), 0, stream, W1, wsb);
    hipLaunchKernelGGL(pq_gemm, dim3(PB + QB), dim3(256), 0, stream, xin, xcmp, b1, wsb);
    hipLaunchKernelGGL(edge_mlp, dim3(EGRID),  dim3(256), 0, stream,
                       wsb, eidx, eidx + NE, W2, b2, out);
}

// Round 4
// 112.002 us; speedup vs baseline: 1.5109x; 1.5109x over previous
//
#include <hip/hip_runtime.h>

// CompoundClassifier, round 11: cut edge-kernel VALU overhead.
//   P = x_ing @ W1[:128], Q = x_cmp @ W1[128:] + b1  -> stored as fp8 (1 B/el)
//   out[e] = sigmoid( relu(P[s]+Q[d]) . W2 + b2 )
// r10 measurement: edge_mlp single-pass ~28-30us, VALUBusy 68%, HBM 7%,
// FETCH 29.4MB (= idx stream + tables once) -> VALU-issue-bound; tables are
// L2-resident; gather latency already hidden. The issue budget is dominated
// by per-pass overhead (precise expf+div sigmoid ~20-25 insts issued
// wave-wide, idx bounds branches, loop bookkeeping) amortized over only
// 8 edges/wave-pass.
// r11: (1) native sigmoid rcp(1+exp2(-x*log2e)) = 4 VALU, (2) branch-free
// 16-pass structure with clamped idx loads (store-mask only pass 15),
// (3) 2 passes per iteration (16 edges/wave-iter) with depth-2 row pipeline.

#define H  128
#define NI 20000
#define NC 10000
#define NE 1000000

typedef _Float16 half8   __attribute__((ext_vector_type(8)));
typedef float    floatx2 __attribute__((ext_vector_type(2)));
typedef float    floatx4 __attribute__((ext_vector_type(4)));

// ws byte layout
#define P8_OFF    0
#define Q8_OFF    (NI * H)                    // 2,560,000
#define WFRAG_B   ((NI + NC) * H)             // 3,840,000 (16B aligned)
// WFRAG: W1 as f16 in MFMA B-fragment order, 64 KB:
//   flat = ((isQ*8 + w*2+nt)*4 + ks)*512 + lane*8 + j
//   holds W1[k][n], k = isQ*128 + ks*32 + (lane>>4)*8 + j,
//                   n = (w)*32 + nt*16 + (lane&15)         (w*2+nt = ntw)

#define PB (NI / 16)   // 1250
#define QB (NC / 16)   // 625

// ---------- fp8 e4m3 helpers (HW path on gfx950; SW fallback for safety) ----
#if __has_builtin(__builtin_amdgcn_cvt_pk_f32_fp8) && __has_builtin(__builtin_amdgcn_cvt_pk_fp8_f32)
#define HW_FP8 1
#else
#define HW_FP8 0
__device__ inline unsigned char enc_e4m3(float x) {
    unsigned s = x < 0.0f ? 0x80u : 0u;
    float a = fminf(fabsf(x), 448.0f);
    if (a < 0.0009765625f) return (unsigned char)s;       // < 2^-10 -> 0
    int e; float m = frexpf(a, &e);                       // a = m*2^e, m in [0.5,1)
    int E = e + 6;                                        // biased exp
    if (E <= 0) {                                         // subnormal: f*2^-9
        int f = (int)rintf(a * 512.0f);
        if (f > 7) return (unsigned char)(s | 0x08);
        return (unsigned char)(s | f);
    }
    int f = (int)rintf((m * 2.0f - 1.0f) * 8.0f);
    if (f == 8) { f = 0; ++E; }
    if (E > 15 || (E == 15 && f > 6)) { E = 15; f = 6; }  // clamp to 448
    return (unsigned char)(s | (E << 3) | f);
}
__device__ inline float dec_e4m3(unsigned char b) {
    int E = (b >> 3) & 15, f = b & 7;
    float v = (E == 0) ? (float)f * 0.001953125f          // f * 2^-9
                       : (float)(8 + f) * exp2f((float)(E - 10));
    return (b & 0x80) ? -v : v;
}
#endif

__device__ inline floatx2 relu2(floatx2 v) {
#if __has_builtin(__builtin_elementwise_max)
    floatx2 z = {0.0f, 0.0f};
    return __builtin_elementwise_max(v, z);
#else
    floatx2 r = { fmaxf(v.x, 0.0f), fmaxf(v.y, 0.0f) };
    return r;
#endif
}

__device__ __forceinline__ float fast_sigmoid(float x) {
#if __has_builtin(__builtin_amdgcn_exp2f) && __has_builtin(__builtin_amdgcn_rcpf)
    const float t = __builtin_amdgcn_exp2f(-1.4426950408889634f * x);
    return __builtin_amdgcn_rcpf(1.0f + t);
#else
    return 1.0f / (1.0f + __expf(-x));
#endif
}

// ---------- one-shot: W1 -> f16 fragment-ordered table ----------
__launch_bounds__(256)
__global__ void cvt_w(const float* __restrict__ W1,   // [256][128] row-major
                      unsigned char* __restrict__ wsb) {
    const int flat = blockIdx.x * 256 + threadIdx.x;   // over 32768
    const int j    = flat & 7;
    const int lane = (flat >> 3) & 63;
    const int ks   = (flat >> 9) & 3;
    const int ntw  = (flat >> 11) & 7;
    const int isQ  = (flat >> 14) & 1;
    const int n = (ntw >> 1) * 32 + (ntw & 1) * 16 + (lane & 15);
    const int k = isQ * 128 + ks * 32 + (lane >> 4) * 8 + j;
    ((_Float16*)(wsb + WFRAG_B))[flat] = (_Float16)W1[k * H + n];
}

// ---------- P/Q precompute: 16x16x32 f16 MFMA, fp8 epilogue ----------
__launch_bounds__(256)
__global__ void pq_gemm(const float* __restrict__ xin,
                        const float* __restrict__ xcmp,
                        const float* __restrict__ b1,
                        unsigned char* __restrict__ wsb) {
    const int b    = blockIdx.x;
    const bool isQ = (b >= PB);
    const int  rb  = (isQ ? b - PB : b) * 16;
    const float* X = isQ ? xcmp : xin;
    unsigned char* OUT8 = wsb + (isQ ? Q8_OFF : P8_OFF);
    const _Float16* wfrag = (const _Float16*)(wsb + WFRAG_B);

    const int lane = threadIdx.x & 63;
    const int w    = threadIdx.x >> 6;
    const int quad = lane >> 4;
    const int m    = lane & 15;

    // B-fragments: lane-contiguous b128 from the fragment-ordered table
    half8 bf[2][4];
    float b1v[2];
#pragma unroll
    for (int nt = 0; nt < 2; ++nt) {
        const int ntw = w * 2 + nt;
#pragma unroll
        for (int ks = 0; ks < 4; ++ks)
            bf[nt][ks] = *(const half8*)(wfrag + (((isQ ? 8 : 0) + ntw) * 4 + ks) * 512 + lane * 8);
        const int n = w * 32 + nt * 16 + m;
        b1v[nt] = isQ ? b1[n] : 0.0f;
    }

    // A-fragments: row rb+m, contiguous 8 floats -> half8
    half8 af[4];
    const float* xr = X + (long)(rb + m) * H + quad * 8;
#pragma unroll
    for (int ks = 0; ks < 4; ++ks) {
        float4 a = *(const float4*)(xr + ks * 32);
        float4 c = *(const float4*)(xr + ks * 32 + 4);
        half8 v = { (_Float16)a.x, (_Float16)a.y, (_Float16)a.z, (_Float16)a.w,
                    (_Float16)c.x, (_Float16)c.y, (_Float16)c.z, (_Float16)c.w };
        af[ks] = v;
    }

    floatx4 acc[2] = { (floatx4)0.0f, (floatx4)0.0f };
#pragma unroll
    for (int ks = 0; ks < 4; ++ks)
#pragma unroll
        for (int nt = 0; nt < 2; ++nt)
            acc[nt] = __builtin_amdgcn_mfma_f32_16x16x32_f16(af[ks], bf[nt][ks], acc[nt], 0, 0, 0);

    // epilogue: +b1, encode fp8, byte stores (rows contiguous in m -> coalesced)
    // C/D: col = lane&15 within n-tile, row = quad*4 + r
#pragma unroll
    for (int nt = 0; nt < 2; ++nt) {
        const int col = w * 32 + nt * 16 + m;
#pragma unroll
        for (int r = 0; r < 4; ++r) {
            const float v = acc[nt][r] + b1v[nt];
#if HW_FP8
            const unsigned u = (unsigned)__builtin_amdgcn_cvt_pk_fp8_f32(v, v, 0, false);
            OUT8[(rb + quad * 4 + r) * H + col] = (unsigned char)(u & 0xff);
#else
            OUT8[(rb + quad * 4 + r) * H + col] = enc_e4m3(v);
#endif
        }
    }
}

// ---------- edge kernel: 8 lanes/edge, branch-free 16-pass, unroll-2 ----------
#define EGRID 2048
#define ESTEP (32 * EGRID)          // 65536 edges per device pass
// NE = 1,000,000 = 15 full passes (k=0..14) + tail pass k=15 (16,960 edges)

__launch_bounds__(256)
__global__ void edge_mlp(const unsigned char* __restrict__ wsb,
                         const int* __restrict__ src_idx,
                         const int* __restrict__ dst_idx,
                         const float* __restrict__ W2,
                         const float* __restrict__ b2p,
                         float* __restrict__ out) {
    const int tid  = threadIdx.x;
    const int c    = tid & 7;       // 16-byte slice of the 128-B row
    const int slot = tid >> 3;      // edge within block-pass (0..31)

    // W2 slice: 16 floats for cols c*16..c*16+15 (regs, reused 16 passes)
    floatx2 w2v[8];
#pragma unroll
    for (int i = 0; i < 8; ++i) w2v[i] = *(const floatx2*)(W2 + c * 16 + i * 2);
    const float b2v = b2p[0];

    const unsigned char* P8 = wsb + P8_OFF;
    const unsigned char* Q8 = wsb + Q8_OFF;
    const int ebase = blockIdx.x * 32 + slot;   // < 65536

    // clamped (branch-free) index load: OOB passes read edge NE-1, store-masked
#define LDIDX(K, SI, DI) do {                                        \
        int _e = ebase + (K) * ESTEP;                                \
        _e = _e < NE ? _e : NE - 1;                                  \
        SI = __builtin_nontemporal_load(src_idx + _e);               \
        DI = __builtin_nontemporal_load(dst_idx + _e);               \
    } while (0)

#define GATHER(SI, DI, PD, QD) do {                                  \
        PD = *(const uint4*)(P8 + (SI) * H + c * 16);                \
        QD = *(const uint4*)(Q8 + (DI) * H + c * 16);                \
    } while (0)

#define COMPUTE(K, PD, QD, MASKED) do {                              \
        floatx2 acc2 = {0.0f, 0.0f};                                 \
        const unsigned pw[4] = { PD.x, PD.y, PD.z, PD.w };           \
        const unsigned qw[4] = { QD.x, QD.y, QD.z, QD.w };           \
        _Pragma("unroll")                                            \
        for (int jw = 0; jw < 4; ++jw) {                             \
            floatx2 pl, ph, ql, qh;                                  \
            DECODE(pw[jw], qw[jw], pl, ph, ql, qh);                  \
            acc2 += relu2(pl + ql) * w2v[2 * jw];                    \
            acc2 += relu2(ph + qh) * w2v[2 * jw + 1];                \
        }                                                            \
        float acc = acc2.x + acc2.y;                                 \
        acc += __shfl_xor(acc, 1);                                   \
        acc += __shfl_xor(acc, 2);                                   \
        acc += __shfl_xor(acc, 4);                                   \
        const int _e = ebase + (K) * ESTEP;                          \
        if (c == 0 && (!(MASKED) || _e < NE)) {                      \
            const float r = fast_sigmoid(acc + b2v);                 \
            __builtin_nontemporal_store(r, out + _e);                \
        }                                                            \
    } while (0)

#if HW_FP8
#define DECODE(PW, QW, PL, PH, QL, QH) do {                          \
        PL = __builtin_amdgcn_cvt_pk_f32_fp8((int)(PW), false);      \
        PH = __builtin_amdgcn_cvt_pk_f32_fp8((int)(PW), true);       \
        QL = __builtin_amdgcn_cvt_pk_f32_fp8((int)(QW), false);      \
        QH = __builtin_amdgcn_cvt_pk_f32_fp8((int)(QW), true);       \
    } while (0)
#else
#define DECODE(PW, QW, PL, PH, QL, QH) do {                          \
        PL = { dec_e4m3((PW) & 0xff), dec_e4m3(((PW) >> 8) & 0xff) };  \
        PH = { dec_e4m3(((PW) >> 16) & 0xff), dec_e4m3((PW) >> 24) };  \
        QL = { dec_e4m3((QW) & 0xff), dec_e4m3(((QW) >> 8) & 0xff) };  \
        QH = { dec_e4m3(((QW) >> 16) & 0xff), dec_e4m3((QW) >> 24) };  \
    } while (0)
#endif

    // ---- prologue: rows(0,1) + idx(2,3) in flight ----
    int siA, diA, siB, diB, si2, di2, si3, di3;
    uint4 pdA, qdA, pdB, qdB;
    LDIDX(0, siA, diA);
    LDIDX(1, siB, diB);
    GATHER(siA, diA, pdA, qdA);
    GATHER(siB, diB, pdB, qdB);
    LDIDX(2, si2, di2);
    LDIDX(3, si3, di3);

    // ---- main: 7 iterations x 2 passes = k 0..13 (all full) ----
#pragma unroll 1
    for (int i = 0; i < 7; ++i) {
        const int k = 2 * i;
        uint4 pdC, qdC, pdD, qdD;
        GATHER(si2, di2, pdC, qdC);          // rows k+2
        GATHER(si3, di3, pdD, qdD);          // rows k+3
        LDIDX(k + 4, si2, di2);              // idx k+4 (clamped; k+4<=17)
        LDIDX(k + 5, si3, di3);              // idx k+5
        COMPUTE(k,     pdA, qdA, false);
        COMPUTE(k + 1, pdB, qdB, false);
        pdA = pdC; qdA = qdC; pdB = pdD; qdB = qdD;
    }

    // ---- epilogue: k=14 (full), k=15 (tail, store-masked) ----
    COMPUTE(14, pdA, qdA, false);
    COMPUTE(15, pdB, qdB, true);

#undef LDIDX
#undef GATHER
#undef COMPUTE
#undef DECODE
}

extern "C" void kernel_launch(void* const* d_in, const int* in_sizes, int n_in,
                              void* d_out, int out_size, void* d_ws, size_t ws_size,
                              hipStream_t stream) {
    const float* xin  = (const float*)d_in[0];
    const float* xcmp = (const float*)d_in[1];
    const int*   eidx = (const int*)d_in[2];    // [2,E]: first E src, next E dst
    const float* W1   = (const float*)d_in[3];
    const float* b1   = (const float*)d_in[4];
    const float* W2   = (const float*)d_in[5];
    const float* b2   = (const float*)d_in[6];
    float* out = (float*)d_out;
    unsigned char* wsb = (unsigned char*)d_ws;  // ~3.9 MB used

    hipLaunchKernelGGL(cvt_w,   dim3(128),     dim3(256), 0, stream, W1, wsb);
    hipLaunchKernelGGL(pq_gemm, dim3(PB + QB), dim3(256), 0, stream, xin, xcmp, b1, wsb);
    hipLaunchKernelGGL(edge_mlp, dim3(EGRID),  dim3(256), 0, stream,
                       wsb, eidx, eidx + NE, W2, b2, out);
}